// Round 13
// baseline (423.717 us; speedup 1.0000x reference)
//
#include <hip/hip_runtime.h>
#include <hip/hip_bf16.h>
#include <stdint.h>

#define L 4096
#define C 256
#define NH 4
#define F3 768
#define KC 1024

typedef __attribute__((ext_vector_type(4))) float f32x4;
typedef __attribute__((ext_vector_type(8))) short short8;
typedef unsigned short u16;

__device__ __forceinline__ u16 f2bf(float f) {
  union { float f; unsigned u; } v; v.f = f;
  unsigned r = v.u + 0x7FFFu + ((v.u >> 16) & 1u);
  return (u16)(r >> 16);
}
__device__ __forceinline__ float bf2f(u16 b) {
  union { unsigned u; float f; } v; v.u = ((unsigned)b) << 16;
  return v.f;
}
__device__ __forceinline__ u16 f2bf_rne(float f) {
  __hip_bfloat16 h = __float2bfloat16(f);
  return *(u16*)&h;
}

// async global->LDS: 64 lanes x 16B. LDS dest is the WAVE-UNIFORM base; HW places
// lane i at base + i*16 (m104/m108). Global source address is per-lane (m173).
__device__ __forceinline__ void glds16(const u16* g, u16* lds_base_uniform) {
  __builtin_amdgcn_global_load_lds(
      (const __attribute__((address_space(1))) void*)g,
      (__attribute__((address_space(3))) void*)lds_base_uniform, 16, 0, 0);
}

// ---------------- misc small kernels ----------------

__global__ __launch_bounds__(256) void tobf16_kernel(const float* __restrict__ src, u16* __restrict__ dst, long n) {
  long i = ((long)blockIdx.x * 256 + threadIdx.x) * 8;
  if (i >= n) return;
  float4 a = *(const float4*)(src + i);
  float4 c = *(const float4*)(src + i + 4);
  u16 o[8] = {f2bf(a.x),f2bf(a.y),f2bf(a.z),f2bf(a.w),f2bf(c.x),f2bf(c.y),f2bf(c.z),f2bf(c.w)};
  *(int4*)(dst + i) = *(int4*)o;
}

__global__ __launch_bounds__(256) void transpose_w_kernel(const float* __restrict__ src, u16* __restrict__ dst, int F) {
  int idx = blockIdx.x * 256 + threadIdx.x;
  if (idx >= F * KC) return;
  int f = idx / KC, kc = idx - f * KC;
  dst[idx] = f2bf(src[(long)kc * F + f]);
}

__global__ __launch_bounds__(256) void gn_stats(const float* __restrict__ x, float* __restrict__ st) {
  const int b = blockIdx.x >> 5, g = blockIdx.x & 31, ch = blockIdx.y;
  const int tid = threadIdx.x;
  const float* xb = x + (long)b * L * C + g * 8;
  float s = 0.f, sq = 0.f;
  for (int l = ch * 512 + tid; l < ch * 512 + 512; l += 256) {
    const float4* p = (const float4*)(xb + (long)l * C);
    float4 a = p[0], c = p[1];
    s  += a.x + a.y + a.z + a.w + c.x + c.y + c.z + c.w;
    sq += a.x*a.x + a.y*a.y + a.z*a.z + a.w*a.w + c.x*c.x + c.y*c.y + c.z*c.z + c.w*c.w;
  }
  __shared__ float rs[256], rq[256];
  rs[tid] = s; rq[tid] = sq;
  __syncthreads();
  for (int o = 128; o > 0; o >>= 1) {
    if (tid < o) { rs[tid] += rs[tid + o]; rq[tid] += rq[tid + o]; }
    __syncthreads();
  }
  if (tid == 0) {
    st[(blockIdx.x * 8 + ch) * 2 + 0] = rs[0];
    st[(blockIdx.x * 8 + ch) * 2 + 1] = rq[0];
  }
}

__global__ __launch_bounds__(256) void gn_apply(const float* __restrict__ x, const float* __restrict__ gamma,
                                                const float* __restrict__ beta, const float* __restrict__ st,
                                                u16* __restrict__ normT, u16* __restrict__ xt_nt) {
  const int b = blockIdx.x >> 5, g = blockIdx.x & 31, ch = blockIdx.y;
  const int tid = threadIdx.x;
  float s = 0.f, sq = 0.f;
#pragma unroll
  for (int j = 0; j < 8; ++j) {
    s  += st[(blockIdx.x * 8 + j) * 2 + 0];
    sq += st[(blockIdx.x * 8 + j) * 2 + 1];
  }
  const float mean = s * (1.f / 32768.f);
  const float var  = sq * (1.f / 32768.f) - mean * mean;
  const float rsig = rsqrtf(var + 1e-5f);
  float gm[8], bt[8];
#pragma unroll
  for (int j = 0; j < 8; ++j) { gm[j] = gamma[g*8+j] * rsig; bt[j] = beta[g*8+j]; }
  const float* xb = x + (long)b * L * C + g * 8;
  for (int l = ch * 512 + tid; l < ch * 512 + 512; l += 256) {
    const float4* p = (const float4*)(xb + (long)l * C);
    float4 a = p[0], c = p[1];
    float v[8] = {a.x,a.y,a.z,a.w,c.x,c.y,c.z,c.w};
    u16 o8[8];
#pragma unroll
    for (int j = 0; j < 8; ++j) o8[j] = f2bf((v[j] - mean) * gm[j] + bt[j]);
    *(int4*)(xt_nt + ((long)b * L + l) * KC + g * 8) = *(int4*)o8;
#pragma unroll
    for (int j = 0; j < 8; ++j) normT[(long)(b * C + g * 8 + j) * L + l] = o8[j];
  }
}

// ---------------- GEMM: C[M,N] = A[M,K] @ BT[N,K]^T (R9-verified core, BN=64) ----------------
#define BM 128
#define BN 64
#define BK 64

// OUT_BF16: bf16 output. QSCALE: multiply Q columns (col%192<64) by 1/16.
// SPLITK: grid.z K-chunks of length Kc, BF16 partials at Cv + z*M*N.
template<int OUT_BF16, int QSCALE, int SPLITK>
__global__ __launch_bounds__(256) void gemm_bt(const u16* __restrict__ A, const u16* __restrict__ BT,
                                               void* __restrict__ Cv, int M, int N, int Kc, int Ktot) {
  __shared__ u16 Al[BM * BK];
  __shared__ u16 Bl[BN * BK];
  const int tid = threadIdx.x;
  const int lane = tid & 63;
  const int wid = tid >> 6;
  const int wr = (wid >> 1) * 64;
  const int wc = (wid & 1) * 32;
  const long bm = (long)blockIdx.x * BM;
  const long bn = (long)blockIdx.y * BN;
  const int k_beg = SPLITK ? blockIdx.z * Kc : 0;
  const int k_end = k_beg + Kc;
  const int jrow = lane & 15, jk = lane >> 4;
  const int lr8 = lane >> 3, lsl = lane & 7;   // within-chunk row, linear slot
  f32x4 acc[4][2] = {};

  for (int k0 = k_beg; k0 < k_end; k0 += BK) {
    // A: 16 chunks of 1KB (8 rows x 128B); wave w stages chunks 4w..4w+3.
    // B: 8 chunks; wave w stages chunks 2w..2w+1.
    // LDS dest = UNIFORM chunk base (lane i lands at base+i*16 => row=i>>3, slot=i&7).
    // Global source pre-swizzled so LDS[r][x] = global[r][x ^ (r&7)], matching reads.
#pragma unroll
    for (int j = 0; j < 4; ++j) {
      int chunk = wid * 4 + j;
      int r = chunk * 8 + lr8;
      glds16(A + (bm + r) * (long)Ktot + k0 + ((lsl ^ (r & 7)) * 8), Al + chunk * 512);
    }
#pragma unroll
    for (int j = 0; j < 2; ++j) {
      int chunk = wid * 2 + j;
      int r = chunk * 8 + lr8;
      glds16(BT + (bn + r) * (long)Ktot + k0 + ((lsl ^ (r & 7)) * 8), Bl + chunk * 512);
    }
    __syncthreads();   // drains vmcnt(0) incl. global_load_lds before LDS reads
    short8 af[4][2], bfr[2][2];
#pragma unroll
    for (int rt = 0; rt < 4; ++rt)
#pragma unroll
      for (int kc = 0; kc < 2; ++kc) {
        int r = wr + rt * 16 + jrow;
        int sl = kc * 4 + jk;
        af[rt][kc] = *(short8*)(Al + r * 64 + ((sl ^ (r & 7)) * 8));
      }
#pragma unroll
    for (int ct = 0; ct < 2; ++ct)
#pragma unroll
      for (int kc = 0; kc < 2; ++kc) {
        int r = wc + ct * 16 + jrow;
        int sl = kc * 4 + jk;
        bfr[ct][kc] = *(short8*)(Bl + r * 64 + ((sl ^ (r & 7)) * 8));
      }
#pragma unroll
    for (int kc = 0; kc < 2; ++kc)
#pragma unroll
      for (int rt = 0; rt < 4; ++rt)
#pragma unroll
        for (int ct = 0; ct < 2; ++ct)
          acc[rt][ct] = __builtin_amdgcn_mfma_f32_16x16x32_bf16(af[rt][kc], bfr[ct][kc], acc[rt][ct], 0, 0, 0);
    __syncthreads();
  }
#pragma unroll
  for (int rt = 0; rt < 4; ++rt)
#pragma unroll
    for (int ct = 0; ct < 2; ++ct)
#pragma unroll
      for (int r = 0; r < 4; ++r) {
        long row = bm + wr + rt * 16 + 4 * jk + r;
        long col = bn + wc + ct * 16 + jrow;
        float v = acc[rt][ct][r];
        if (QSCALE) { if ((int)(col % 192) < 64) v *= 0.0625f; }
        if (SPLITK) ((u16*)Cv)[(long)blockIdx.z * M * N + row * N + col] = f2bf(v);
        else if (OUT_BF16) ((u16*)Cv)[row * N + col] = f2bf(v);
        else ((float*)Cv)[row * N + col] = v;
      }
}

// ---------------- Chebyshev combine (sums 2 bf16 split-K partials) + transpose ----------------
__global__ __launch_bounds__(256) void cheb_combine(const u16* __restrict__ Yp, const u16* __restrict__ prevT,
                                                    u16* __restrict__ outT, u16* __restrict__ xt_nt,
                                                    int kslot, float coef) {
  __shared__ u16 t[64][65];
  const int r0 = blockIdx.x * 64, c0 = blockIdx.y * 64;
  const int tid = threadIdx.x;
  const long pl = 512L * L;
#pragma unroll
  for (int s = 0; s < 16; ++s) {
    int idx = s * 256 + tid;
    int r = idx >> 6, c = idx & 63;
    long off = (long)(r0 + r) * L + c0 + c;
    float v = coef * (bf2f(Yp[off]) + bf2f(Yp[pl + off]));
    if (prevT) v -= bf2f(prevT[off]);
    u16 u = f2bf(v);
    outT[off] = u;
    t[r][c] = u;
  }
  __syncthreads();
  const int b = r0 >> 8, ch0 = r0 & 255;
#pragma unroll
  for (int s = 0; s < 16; ++s) {
    int idx = s * 256 + tid;
    int lr = idx >> 6, cc = idx & 63;
    xt_nt[((long)b * L + c0 + lr) * KC + kslot * C + ch0 + cc] = t[cc][lr];
  }
}

// final: out = sum of 2 bf16 wout partials + x (fp32). grid 2048
__global__ __launch_bounds__(256) void out_combine(const u16* __restrict__ Yp, const float* __restrict__ x,
                                                   float* __restrict__ out) {
  const long pl = 2097152L; // 8192*256
  long i = ((long)blockIdx.x * 256 + threadIdx.x) * 4;
  uint2 w0 = *(const uint2*)(Yp + i);
  uint2 w1 = *(const uint2*)(Yp + pl + i);
  const u16* a = (const u16*)&w0;
  const u16* b = (const u16*)&w1;
  float4 xr = *(const float4*)(x + i);
  float4 o;
  o.x = bf2f(a[0]) + bf2f(b[0]) + xr.x;
  o.y = bf2f(a[1]) + bf2f(b[1]) + xr.y;
  o.z = bf2f(a[2]) + bf2f(b[2]) + xr.z;
  o.w = bf2f(a[3]) + bf2f(b[3]) + xr.w;
  *(float4*)(out + i) = o;
}

// V transpose: VT[(b*4+h)*64 + c, m] = qkv[b, m, h*192+128+c]
__global__ __launch_bounds__(256) void vt_kernel(const u16* __restrict__ qkv, u16* __restrict__ VT) {
  __shared__ u16 t[64][65];
  const int bh = blockIdx.x;
  const int b = bh >> 2, h = bh & 3;
  const int m0 = blockIdx.y * 64;
  const int tid = threadIdx.x;
#pragma unroll
  for (int s = 0; s < 16; ++s) {
    int idx = s * 256 + tid; int mr = idx >> 6, cc = idx & 63;
    t[mr][cc] = qkv[((long)b * L + m0 + mr) * F3 + h * 192 + 128 + cc];
  }
  __syncthreads();
#pragma unroll
  for (int s = 0; s < 16; ++s) {
    int idx = s * 256 + tid; int cr = idx >> 6, mm = idx & 63;
    VT[((long)bh * 64 + cr) * L + m0 + mm] = t[mm][cr];
  }
}

// ---------------- fused attention: QBLK=64, swapped-QK (S^T), vectorized P stores ----------------
// grid (L/64, 4 [g], B), 4 waves = 4 heads. Q pre-scaled by 1/16 in qkv GEMM; fixed max=0.
__global__ __launch_bounds__(256) void attn_kernel(const u16* __restrict__ qkv, const u16* __restrict__ VT,
                                                   u16* __restrict__ part) {
  const int b = blockIdx.z;
  const int g = blockIdx.y;
  const int l0 = blockIdx.x * 64;
  const int tid = threadIdx.x;
  const int lane = tid & 63;
  const int h = tid >> 6;
  const int jrow = lane & 15, jk = lane >> 4;

  __shared__ u16 P_lds[4][64][72];
  __shared__ float ssm[4][64];

  short8 aq[4][2];
#pragma unroll
  for (int rt = 0; rt < 4; ++rt)
#pragma unroll
    for (int kc = 0; kc < 2; ++kc)
      aq[rt][kc] = *(const short8*)(qkv + ((long)b * L + l0 + rt * 16 + jrow) * F3 + h * 192 + kc * 32 + jk * 8);

  const u16* Kbase = qkv + (long)b * L * F3 + h * 192 + 64;
  const u16* Vbase = VT + (long)(b * 4 + h) * 64 * L;

  f32x4 gac[4][4] = {};
  float psum[4] = {0.f, 0.f, 0.f, 0.f};

#pragma unroll 2
  for (int mc = 0; mc < 16; ++mc) {
    const int m0 = g * 1024 + mc * 64;
    short8 kf[4][2];
#pragma unroll
    for (int kt = 0; kt < 4; ++kt)
#pragma unroll
      for (int kc = 0; kc < 2; ++kc)
        kf[kt][kc] = *(const short8*)(Kbase + (long)(m0 + kt * 16 + jrow) * F3 + kc * 32 + jk * 8);
    short8 vf[4][2];
#pragma unroll
    for (int ct = 0; ct < 4; ++ct)
#pragma unroll
      for (int km = 0; km < 2; ++km)
        vf[ct][km] = *(const short8*)(Vbase + (long)(ct * 16 + jrow) * L + m0 + km * 32 + jk * 8);

    // S^T = K @ Q^T (operand-swapped, both x32 verified): C[i=m][j=q]
#pragma unroll
    for (int rt = 0; rt < 4; ++rt) {
      f32x4 st[4] = {};
#pragma unroll
      for (int kc = 0; kc < 2; ++kc)
#pragma unroll
        for (int kt = 0; kt < 4; ++kt)
          st[kt] = __builtin_amdgcn_mfma_f32_16x16x32_bf16(kf[kt][kc], aq[rt][kc], st[kt], 0, 0, 0);
#pragma unroll
      for (int kt = 0; kt < 4; ++kt) {
        float p0 = __expf(st[kt][0]);
        float p1 = __expf(st[kt][1]);
        float p2 = __expf(st[kt][2]);
        float p3 = __expf(st[kt][3]);
        psum[rt] += (p0 + p1) + (p2 + p3);
        u16 pk[4] = {f2bf_rne(p0), f2bf_rne(p1), f2bf_rne(p2), f2bf_rne(p3)};
        *(uint2*)&P_lds[h][rt * 16 + jrow][kt * 16 + jk * 4] = *(uint2*)pk;
      }
    }
    // PV: pa = A-operand rows q, k = m contiguous
    short8 pa[4][2];
#pragma unroll
    for (int rt = 0; rt < 4; ++rt)
#pragma unroll
      for (int km = 0; km < 2; ++km)
        pa[rt][km] = *(short8*)&P_lds[h][rt * 16 + jrow][km * 32 + jk * 8];
#pragma unroll
    for (int km = 0; km < 2; ++km)
#pragma unroll
      for (int rt = 0; rt < 4; ++rt)
#pragma unroll
        for (int ct = 0; ct < 4; ++ct)
          gac[rt][ct] = __builtin_amdgcn_mfma_f32_16x16x32_bf16(pa[rt][km], vf[ct][km], gac[rt][ct], 0, 0, 0);
  }

#pragma unroll
  for (int rt = 0; rt < 4; ++rt) {
    float s = psum[rt];
    s += __shfl_xor(s, 16);
    s += __shfl_xor(s, 32);
    psum[rt] = s;
  }
  if (jk == 0) {
#pragma unroll
    for (int rt = 0; rt < 4; ++rt) ssm[h][rt * 16 + jrow] = psum[rt];
  }
  __syncthreads();
  float scl[4][4];
#pragma unroll
  for (int rt = 0; rt < 4; ++rt)
#pragma unroll
    for (int r = 0; r < 4; ++r) {
      int row = rt * 16 + jk * 4 + r;   // PV output row = q
      scl[rt][r] = 1.f / (ssm[0][row] + ssm[1][row] + ssm[2][row] + ssm[3][row]);
    }
#pragma unroll
  for (int rt = 0; rt < 4; ++rt)
#pragma unroll
    for (int ct = 0; ct < 4; ++ct) {
      u16 pk[4];
#pragma unroll
      for (int r = 0; r < 4; ++r) pk[r] = f2bf_rne(gac[rt][ct][r] * scl[rt][r]);
      *(uint2*)(part + (long)g * (512L * L)
                + (long)(b * C + h * 64 + ct * 16 + jrow) * L + l0 + rt * 16 + jk * 4) = *(uint2*)pk;
    }
}

// sum 4 per-g bf16 partials -> attnT bf16 [B*C, L] + xt_nt slot 0 (transposed)
__global__ __launch_bounds__(256) void attn_reduce(const u16* __restrict__ part, u16* __restrict__ attnT,
                                                   u16* __restrict__ xt_nt) {
  __shared__ u16 t[64][65];
  const int r0 = blockIdx.x * 64, c0 = blockIdx.y * 64;
  const int tid = threadIdx.x;
  const long gs = 512L * L;
#pragma unroll
  for (int s = 0; s < 16; ++s) {
    int idx = s * 256 + tid;
    int r = idx >> 6, c = idx & 63;
    long off = (long)(r0 + r) * L + c0 + c;
    float v = bf2f(part[off]) + bf2f(part[gs + off]) + bf2f(part[2 * gs + off]) + bf2f(part[3 * gs + off]);
    u16 u = f2bf(v);
    attnT[off] = u;
    t[r][c] = u;
  }
  __syncthreads();
  const int b = r0 >> 8, ch0 = r0 & 255;
#pragma unroll
  for (int s = 0; s < 16; ++s) {
    int idx = s * 256 + tid;
    int lr = idx >> 6, cc = idx & 63;
    xt_nt[((long)b * L + c0 + lr) * KC + 0 * C + ch0 + cc] = t[cc][lr];
  }
}

// ---------------- launcher ----------------

extern "C" void kernel_launch(void* const* d_in, const int* in_sizes, int n_in,
                              void* d_out, int out_size, void* d_ws, size_t ws_size,
                              hipStream_t stream) {
  const float* x     = (const float*)d_in[0];
  const float* lap   = (const float*)d_in[1];
  const float* gamma = (const float*)d_in[2];
  const float* beta  = (const float*)d_in[3];
  const float* w_qkv = (const float*)d_in[4];
  const float* w_out = (const float*)d_in[5];
  float* out = (float*)d_out;

  char* ws = (char*)d_ws;
  u16*   lap_bf = (u16*)ws;   ws += (size_t)L * L * 2;              // 32 MiB
  u16*   xt_nt  = (u16*)ws;   ws += (size_t)2 * L * KC * 2;        // 16 MiB
  u16*   xtT0   = (u16*)ws;   ws += (size_t)512 * L * 2;           // 4 MiB
  u16*   xtT1   = (u16*)ws;   ws += (size_t)512 * L * 2;
  u16*   xtT2   = (u16*)ws;   ws += (size_t)512 * L * 2;
  u16*   xtT3   = (u16*)ws;   ws += (size_t)512 * L * 2;
  char*  regA   = ws;         ws += (size_t)32 * 1024 * 1024;      // 32 MiB overlay region
  u16*   WqkvT  = (u16*)ws;   ws += (size_t)F3 * KC * 2;
  u16*   WoutT  = (u16*)ws;   ws += (size_t)C * KC * 2;
  float* gnst   = (float*)ws; ws += (size_t)64 * 8 * 2 * 4;

  // overlays (stream-ordered disjoint lifetimes):
  u16*   Ypart  = (u16*)regA;                          // GEMM bf16 partials (2 x 4.2/8.4 MiB)
  u16*   qkv_bf = (u16*)regA;                          // qkv phase (12 MiB)
  u16*   VTb    = qkv_bf + (size_t)2 * L * F3;         // +4 MiB (ends exactly at 16 MiB)
  u16*   part   = (u16*)(regA + 16777216);             // attn bf16 partials [4][512][L] (16 MiB)
                                                       // DISJOINT from qkv_bf+VTb

  tobf16_kernel<<<dim3(8192), dim3(256), 0, stream>>>(lap, lap_bf, (long)L * L);
  transpose_w_kernel<<<dim3((F3 * KC + 255) / 256), dim3(256), 0, stream>>>(w_qkv, WqkvT, F3);
  transpose_w_kernel<<<dim3((C * KC + 255) / 256), dim3(256), 0, stream>>>(w_out, WoutT, C);
  gn_stats<<<dim3(64, 8), dim3(256), 0, stream>>>(x, gnst);
  gn_apply<<<dim3(64, 8), dim3(256), 0, stream>>>(x, gamma, beta, gnst, xtT0, xt_nt);

  // cheb conv 1 (split-K=2 lap GEMMs, bf16 partials)
  gemm_bt<0,0,1><<<dim3(4, 64, 2), dim3(256), 0, stream>>>(xtT0, lap_bf, Ypart, 512, L, 2048, L);
  cheb_combine<<<dim3(8, 64), dim3(256), 0, stream>>>(Ypart, nullptr, xtT1, xt_nt, 1, 1.f);
  gemm_bt<0,0,1><<<dim3(4, 64, 2), dim3(256), 0, stream>>>(xtT1, lap_bf, Ypart, 512, L, 2048, L);
  cheb_combine<<<dim3(8, 64), dim3(256), 0, stream>>>(Ypart, xtT0, xtT2, xt_nt, 2, 2.f);
  gemm_bt<0,0,1><<<dim3(4, 64, 2), dim3(256), 0, stream>>>(xtT2, lap_bf, Ypart, 512, L, 2048, L);
  cheb_combine<<<dim3(8, 64), dim3(256), 0, stream>>>(Ypart, xtT1, xtT3, xt_nt, 3, 2.f);

  // qkv projection (Q columns pre-scaled by 1/16 for attention): N=768 = 12x64
  gemm_bt<1,1,0><<<dim3(64, 12), dim3(256), 0, stream>>>(xt_nt, WqkvT, qkv_bf, 2 * L, F3, KC, KC);
  vt_kernel<<<dim3(8, 64), dim3(256), 0, stream>>>(qkv_bf, VTb);

  // fused attention (QBLK=64): per-g bf16 partials then reduce (+transpose into xt_nt slot 0)
  attn_kernel<<<dim3(64, 4, 2), dim3(256), 0, stream>>>(qkv_bf, VTb, part);
  attn_reduce<<<dim3(8, 64), dim3(256), 0, stream>>>(part, xtT0, xt_nt);

  // cheb conv 2
  gemm_bt<0,0,1><<<dim3(4, 64, 2), dim3(256), 0, stream>>>(xtT0, lap_bf, Ypart, 512, L, 2048, L);
  cheb_combine<<<dim3(8, 64), dim3(256), 0, stream>>>(Ypart, nullptr, xtT1, xt_nt, 1, 1.f);
  gemm_bt<0,0,1><<<dim3(4, 64, 2), dim3(256), 0, stream>>>(xtT1, lap_bf, Ypart, 512, L, 2048, L);
  cheb_combine<<<dim3(8, 64), dim3(256), 0, stream>>>(Ypart, xtT0, xtT2, xt_nt, 2, 2.f);
  gemm_bt<0,0,1><<<dim3(4, 64, 2), dim3(256), 0, stream>>>(xtT2, lap_bf, Ypart, 512, L, 2048, L);
  cheb_combine<<<dim3(8, 64), dim3(256), 0, stream>>>(Ypart, xtT1, xtT3, xt_nt, 3, 2.f);

  // final projection split-K=2 + residual combine: N=256 = 4x64
  gemm_bt<0,0,1><<<dim3(64, 4, 2), dim3(256), 0, stream>>>(xt_nt, WoutT, Ypart, 2 * L, C, 512, KC);
  out_combine<<<dim3(2048), dim3(256), 0, stream>>>(Ypart, x, out);
}

// Round 14
// 395.214 us; speedup vs baseline: 1.0721x; 1.0721x over previous
//
#include <hip/hip_runtime.h>
#include <hip/hip_bf16.h>
#include <stdint.h>

#define L 4096
#define C 256
#define NH 4
#define F3 768
#define KC 1024

typedef __attribute__((ext_vector_type(4))) float f32x4;
typedef __attribute__((ext_vector_type(8))) short short8;
typedef unsigned short u16;

__device__ __forceinline__ u16 f2bf(float f) {
  union { float f; unsigned u; } v; v.f = f;
  unsigned r = v.u + 0x7FFFu + ((v.u >> 16) & 1u);
  return (u16)(r >> 16);
}
__device__ __forceinline__ float bf2f(u16 b) {
  union { unsigned u; float f; } v; v.u = ((unsigned)b) << 16;
  return v.f;
}
__device__ __forceinline__ u16 f2bf_rne(float f) {
  __hip_bfloat16 h = __float2bfloat16(f);
  return *(u16*)&h;
}

// async global->LDS: 64 lanes x 16B. LDS dest is the WAVE-UNIFORM base; HW places
// lane i at base + i*16 (m104/m108). Global source address is per-lane (m173).
__device__ __forceinline__ void glds16(const u16* g, u16* lds_base_uniform) {
  __builtin_amdgcn_global_load_lds(
      (const __attribute__((address_space(1))) void*)g,
      (__attribute__((address_space(3))) void*)lds_base_uniform, 16, 0, 0);
}

// XCD-aware bijective block swizzle (T1): HW assigns orig -> XCD orig%8; remap so
// each XCD gets a CONTIGUOUS logical range (nwg/8 blocks) whose shared tiles fit
// its private 4 MiB L2. Requires nwg % 8 == 0 (all our grids satisfy this).
__device__ __forceinline__ void xcd_swizzle(int& bx, int& by, int& bz) {
  const int nwg = gridDim.x * gridDim.y * gridDim.z;
  const int orig = blockIdx.x + gridDim.x * (blockIdx.y + gridDim.y * blockIdx.z);
  const int logical = ((orig & 7) * (nwg >> 3)) + (orig >> 3);
  bx = logical % gridDim.x;
  const int t = logical / gridDim.x;
  by = t % gridDim.y;
  bz = t / gridDim.y;
}

// ---------------- misc small kernels ----------------

__global__ __launch_bounds__(256) void tobf16_kernel(const float* __restrict__ src, u16* __restrict__ dst, long n) {
  long i = ((long)blockIdx.x * 256 + threadIdx.x) * 8;
  if (i >= n) return;
  float4 a = *(const float4*)(src + i);
  float4 c = *(const float4*)(src + i + 4);
  u16 o[8] = {f2bf(a.x),f2bf(a.y),f2bf(a.z),f2bf(a.w),f2bf(c.x),f2bf(c.y),f2bf(c.z),f2bf(c.w)};
  *(int4*)(dst + i) = *(int4*)o;
}

__global__ __launch_bounds__(256) void transpose_w_kernel(const float* __restrict__ src, u16* __restrict__ dst, int F) {
  int idx = blockIdx.x * 256 + threadIdx.x;
  if (idx >= F * KC) return;
  int f = idx / KC, kc = idx - f * KC;
  dst[idx] = f2bf(src[(long)kc * F + f]);
}

__global__ __launch_bounds__(256) void gn_stats(const float* __restrict__ x, float* __restrict__ st) {
  const int b = blockIdx.x >> 5, g = blockIdx.x & 31, ch = blockIdx.y;
  const int tid = threadIdx.x;
  const float* xb = x + (long)b * L * C + g * 8;
  float s = 0.f, sq = 0.f;
  for (int l = ch * 512 + tid; l < ch * 512 + 512; l += 256) {
    const float4* p = (const float4*)(xb + (long)l * C);
    float4 a = p[0], c = p[1];
    s  += a.x + a.y + a.z + a.w + c.x + c.y + c.z + c.w;
    sq += a.x*a.x + a.y*a.y + a.z*a.z + a.w*a.w + c.x*c.x + c.y*c.y + c.z*c.z + c.w*c.w;
  }
  __shared__ float rs[256], rq[256];
  rs[tid] = s; rq[tid] = sq;
  __syncthreads();
  for (int o = 128; o > 0; o >>= 1) {
    if (tid < o) { rs[tid] += rs[tid + o]; rq[tid] += rq[tid + o]; }
    __syncthreads();
  }
  if (tid == 0) {
    st[(blockIdx.x * 8 + ch) * 2 + 0] = rs[0];
    st[(blockIdx.x * 8 + ch) * 2 + 1] = rq[0];
  }
}

__global__ __launch_bounds__(256) void gn_apply(const float* __restrict__ x, const float* __restrict__ gamma,
                                                const float* __restrict__ beta, const float* __restrict__ st,
                                                u16* __restrict__ normT, u16* __restrict__ xt_nt) {
  const int b = blockIdx.x >> 5, g = blockIdx.x & 31, ch = blockIdx.y;
  const int tid = threadIdx.x;
  float s = 0.f, sq = 0.f;
#pragma unroll
  for (int j = 0; j < 8; ++j) {
    s  += st[(blockIdx.x * 8 + j) * 2 + 0];
    sq += st[(blockIdx.x * 8 + j) * 2 + 1];
  }
  const float mean = s * (1.f / 32768.f);
  const float var  = sq * (1.f / 32768.f) - mean * mean;
  const float rsig = rsqrtf(var + 1e-5f);
  float gm[8], bt[8];
#pragma unroll
  for (int j = 0; j < 8; ++j) { gm[j] = gamma[g*8+j] * rsig; bt[j] = beta[g*8+j]; }
  const float* xb = x + (long)b * L * C + g * 8;
  for (int l = ch * 512 + tid; l < ch * 512 + 512; l += 256) {
    const float4* p = (const float4*)(xb + (long)l * C);
    float4 a = p[0], c = p[1];
    float v[8] = {a.x,a.y,a.z,a.w,c.x,c.y,c.z,c.w};
    u16 o8[8];
#pragma unroll
    for (int j = 0; j < 8; ++j) o8[j] = f2bf((v[j] - mean) * gm[j] + bt[j]);
    *(int4*)(xt_nt + ((long)b * L + l) * KC + g * 8) = *(int4*)o8;
#pragma unroll
    for (int j = 0; j < 8; ++j) normT[(long)(b * C + g * 8 + j) * L + l] = o8[j];
  }
}

// ---------------- GEMM: C[M,N] = A[M,K] @ BT[N,K]^T, 128x128 tile, glds staging ----------------
#define BM 128
#define BN 128
#define BK 64

// OUT_BF16: bf16 output. QSCALE: multiply Q columns (col%192<64) by 1/16.
// SPLITK: grid.z K-chunks, fp32 partials.
template<int OUT_BF16, int QSCALE, int SPLITK>
__global__ __launch_bounds__(256) void gemm_bt(const u16* __restrict__ A, const u16* __restrict__ BT,
                                               void* __restrict__ Cv, int M, int N, int Kc, int Ktot) {
  __shared__ u16 Al[BM * BK];
  __shared__ u16 Bl[BN * BK];
  int bxi, byi, bzi;
  xcd_swizzle(bxi, byi, bzi);
  const int tid = threadIdx.x;
  const int lane = tid & 63;
  const int wid = tid >> 6;
  const int wr = (wid >> 1) * 64;   // wave row offset (2x2 wave grid, 64x64 per wave)
  const int wc = (wid & 1) * 64;    // wave col offset
  const long bm = (long)bxi * BM;
  const long bn = (long)byi * BN;
  const int k_beg = SPLITK ? bzi * Kc : 0;
  const int k_end = k_beg + Kc;
  const int jrow = lane & 15, jk = lane >> 4;
  const int lr8 = lane >> 3, lsl = lane & 7;   // within-chunk row, linear slot
  f32x4 acc[4][4] = {};

  for (int k0 = k_beg; k0 < k_end; k0 += BK) {
#pragma unroll
    for (int j = 0; j < 4; ++j) {
      int chunk = wid * 4 + j;
      int r = chunk * 8 + lr8;
      glds16(A + (bm + r) * (long)Ktot + k0 + ((lsl ^ (r & 7)) * 8), Al + chunk * 512);
    }
#pragma unroll
    for (int j = 0; j < 4; ++j) {
      int chunk = wid * 4 + j;
      int r = chunk * 8 + lr8;
      glds16(BT + (bn + r) * (long)Ktot + k0 + ((lsl ^ (r & 7)) * 8), Bl + chunk * 512);
    }
    __syncthreads();   // drains vmcnt(0) incl. global_load_lds before LDS reads
    short8 af[4][2], bfr[4][2];
#pragma unroll
    for (int rt = 0; rt < 4; ++rt)
#pragma unroll
      for (int kc = 0; kc < 2; ++kc) {
        int r = wr + rt * 16 + jrow;
        int sl = kc * 4 + jk;
        af[rt][kc] = *(short8*)(Al + r * 64 + ((sl ^ (r & 7)) * 8));
      }
#pragma unroll
    for (int ct = 0; ct < 4; ++ct)
#pragma unroll
      for (int kc = 0; kc < 2; ++kc) {
        int r = wc + ct * 16 + jrow;
        int sl = kc * 4 + jk;
        bfr[ct][kc] = *(short8*)(Bl + r * 64 + ((sl ^ (r & 7)) * 8));
      }
#pragma unroll
    for (int kc = 0; kc < 2; ++kc)
#pragma unroll
      for (int rt = 0; rt < 4; ++rt)
#pragma unroll
        for (int ct = 0; ct < 4; ++ct)
          acc[rt][ct] = __builtin_amdgcn_mfma_f32_16x16x32_bf16(af[rt][kc], bfr[ct][kc], acc[rt][ct], 0, 0, 0);
    __syncthreads();
  }
  float* outf = SPLITK ? ((float*)Cv + (long)bzi * M * N) : (float*)Cv;
#pragma unroll
  for (int rt = 0; rt < 4; ++rt)
#pragma unroll
    for (int ct = 0; ct < 4; ++ct)
#pragma unroll
      for (int r = 0; r < 4; ++r) {
        long row = bm + wr + rt * 16 + 4 * jk + r;
        long col = bn + wc + ct * 16 + jrow;
        float v = acc[rt][ct][r];
        if (QSCALE) { if ((int)(col % 192) < 64) v *= 0.0625f; }
        if (OUT_BF16) ((u16*)Cv)[row * N + col] = f2bf(v);
        else outf[row * N + col] = v;
      }
}

// ---------------- Chebyshev combine (sums 4 split-K partials) + transpose to xt_nt slot ----------------
__global__ __launch_bounds__(256) void cheb_combine(const float* __restrict__ Yp, const u16* __restrict__ prevT,
                                                    u16* __restrict__ outT, u16* __restrict__ xt_nt,
                                                    int kslot, float coef) {
  __shared__ u16 t[64][65];
  const int r0 = blockIdx.x * 64, c0 = blockIdx.y * 64;
  const int tid = threadIdx.x;
  const long pl = 512L * L;
#pragma unroll
  for (int s = 0; s < 16; ++s) {
    int idx = s * 256 + tid;
    int r = idx >> 6, c = idx & 63;
    long off = (long)(r0 + r) * L + c0 + c;
    float v = coef * (Yp[off] + Yp[pl + off] + Yp[2 * pl + off] + Yp[3 * pl + off]);
    if (prevT) v -= bf2f(prevT[off]);
    u16 u = f2bf(v);
    outT[off] = u;
    t[r][c] = u;
  }
  __syncthreads();
  const int b = r0 >> 8, ch0 = r0 & 255;
#pragma unroll
  for (int s = 0; s < 16; ++s) {
    int idx = s * 256 + tid;
    int lr = idx >> 6, cc = idx & 63;
    xt_nt[((long)b * L + c0 + lr) * KC + kslot * C + ch0 + cc] = t[cc][lr];
  }
}

__global__ __launch_bounds__(256) void out_combine(const float* __restrict__ Yp, const float* __restrict__ x,
                                                   float* __restrict__ out) {
  const long pl = 2097152L; // 8192*256
  long i = ((long)blockIdx.x * 256 + threadIdx.x) * 4;
  float4 a = *(const float4*)(Yp + i);
  float4 b = *(const float4*)(Yp + pl + i);
  float4 c = *(const float4*)(Yp + 2 * pl + i);
  float4 d = *(const float4*)(Yp + 3 * pl + i);
  float4 xr = *(const float4*)(x + i);
  float4 o;
  o.x = a.x + b.x + c.x + d.x + xr.x;
  o.y = a.y + b.y + c.y + d.y + xr.y;
  o.z = a.z + b.z + c.z + d.z + xr.z;
  o.w = a.w + b.w + c.w + d.w + xr.w;
  *(float4*)(out + i) = o;
}

// V transpose: VT[(b*4+h)*64 + c, m] = qkv[b, m, h*192+128+c]
__global__ __launch_bounds__(256) void vt_kernel(const u16* __restrict__ qkv, u16* __restrict__ VT) {
  __shared__ u16 t[64][65];
  const int bh = blockIdx.x;
  const int b = bh >> 2, h = bh & 3;
  const int m0 = blockIdx.y * 64;
  const int tid = threadIdx.x;
#pragma unroll
  for (int s = 0; s < 16; ++s) {
    int idx = s * 256 + tid; int mr = idx >> 6, cc = idx & 63;
    t[mr][cc] = qkv[((long)b * L + m0 + mr) * F3 + h * 192 + 128 + cc];
  }
  __syncthreads();
#pragma unroll
  for (int s = 0; s < 16; ++s) {
    int idx = s * 256 + tid; int cr = idx >> 6, mm = idx & 63;
    VT[((long)bh * 64 + cr) * L + m0 + mm] = t[mm][cr];
  }
}

// ---------------- fused attention: QBLK=64, swapped-QK (S^T), vectorized P stores ----------------
// grid (L/64, 4 [g], B), 4 waves = 4 heads. Q pre-scaled by 1/16 in qkv GEMM; fixed max=0.
// XCD swizzle groups all 64 l0-tiles of one (g,b) on one XCD -> its 2 MB K/V slice is L2-resident.
__global__ __launch_bounds__(256) void attn_kernel(const u16* __restrict__ qkv, const u16* __restrict__ VT,
                                                   u16* __restrict__ part) {
  int bxi, byi, bzi;
  xcd_swizzle(bxi, byi, bzi);
  const int b = bzi;
  const int g = byi;
  const int l0 = bxi * 64;
  const int tid = threadIdx.x;
  const int lane = tid & 63;
  const int h = tid >> 6;
  const int jrow = lane & 15, jk = lane >> 4;

  __shared__ u16 P_lds[4][64][72];
  __shared__ float ssm[4][64];

  short8 aq[4][2];
#pragma unroll
  for (int rt = 0; rt < 4; ++rt)
#pragma unroll
    for (int kc = 0; kc < 2; ++kc)
      aq[rt][kc] = *(const short8*)(qkv + ((long)b * L + l0 + rt * 16 + jrow) * F3 + h * 192 + kc * 32 + jk * 8);

  const u16* Kbase = qkv + (long)b * L * F3 + h * 192 + 64;
  const u16* Vbase = VT + (long)(b * 4 + h) * 64 * L;

  f32x4 gac[4][4] = {};
  float psum[4] = {0.f, 0.f, 0.f, 0.f};

#pragma unroll 2
  for (int mc = 0; mc < 16; ++mc) {
    const int m0 = g * 1024 + mc * 64;
    short8 kf[4][2];
#pragma unroll
    for (int kt = 0; kt < 4; ++kt)
#pragma unroll
      for (int kc = 0; kc < 2; ++kc)
        kf[kt][kc] = *(const short8*)(Kbase + (long)(m0 + kt * 16 + jrow) * F3 + kc * 32 + jk * 8);
    short8 vf[4][2];
#pragma unroll
    for (int ct = 0; ct < 4; ++ct)
#pragma unroll
      for (int km = 0; km < 2; ++km)
        vf[ct][km] = *(const short8*)(Vbase + (long)(ct * 16 + jrow) * L + m0 + km * 32 + jk * 8);

    // S^T = K @ Q^T (operand-swapped, both x32 verified): C[i=m][j=q]
#pragma unroll
    for (int rt = 0; rt < 4; ++rt) {
      f32x4 st[4] = {};
#pragma unroll
      for (int kc = 0; kc < 2; ++kc)
#pragma unroll
        for (int kt = 0; kt < 4; ++kt)
          st[kt] = __builtin_amdgcn_mfma_f32_16x16x32_bf16(kf[kt][kc], aq[rt][kc], st[kt], 0, 0, 0);
#pragma unroll
      for (int kt = 0; kt < 4; ++kt) {
        float p0 = __expf(st[kt][0]);
        float p1 = __expf(st[kt][1]);
        float p2 = __expf(st[kt][2]);
        float p3 = __expf(st[kt][3]);
        psum[rt] += (p0 + p1) + (p2 + p3);
        u16 pk[4] = {f2bf_rne(p0), f2bf_rne(p1), f2bf_rne(p2), f2bf_rne(p3)};
        *(uint2*)&P_lds[h][rt * 16 + jrow][kt * 16 + jk * 4] = *(uint2*)pk;
      }
    }
    // PV: pa = A-operand rows q, k = m contiguous
    short8 pa[4][2];
#pragma unroll
    for (int rt = 0; rt < 4; ++rt)
#pragma unroll
      for (int km = 0; km < 2; ++km)
        pa[rt][km] = *(short8*)&P_lds[h][rt * 16 + jrow][km * 32 + jk * 8];
#pragma unroll
    for (int km = 0; km < 2; ++km)
#pragma unroll
      for (int rt = 0; rt < 4; ++rt)
#pragma unroll
        for (int ct = 0; ct < 4; ++ct)
          gac[rt][ct] = __builtin_amdgcn_mfma_f32_16x16x32_bf16(pa[rt][km], vf[ct][km], gac[rt][ct], 0, 0, 0);
  }

#pragma unroll
  for (int rt = 0; rt < 4; ++rt) {
    float s = psum[rt];
    s += __shfl_xor(s, 16);
    s += __shfl_xor(s, 32);
    psum[rt] = s;
  }
  if (jk == 0) {
#pragma unroll
    for (int rt = 0; rt < 4; ++rt) ssm[h][rt * 16 + jrow] = psum[rt];
  }
  __syncthreads();
  float scl[4][4];
#pragma unroll
  for (int rt = 0; rt < 4; ++rt)
#pragma unroll
    for (int r = 0; r < 4; ++r) {
      int row = rt * 16 + jk * 4 + r;   // PV output row = q
      scl[rt][r] = 1.f / (ssm[0][row] + ssm[1][row] + ssm[2][row] + ssm[3][row]);
    }
#pragma unroll
  for (int rt = 0; rt < 4; ++rt)
#pragma unroll
    for (int ct = 0; ct < 4; ++ct) {
      u16 pk[4];
#pragma unroll
      for (int r = 0; r < 4; ++r) pk[r] = f2bf_rne(gac[rt][ct][r] * scl[rt][r]);
      *(uint2*)(part + (long)g * (512L * L)
                + (long)(b * C + h * 64 + ct * 16 + jrow) * L + l0 + rt * 16 + jk * 4) = *(uint2*)pk;
    }
}

// sum 4 per-g bf16 partials -> attnT bf16 [B*C, L] + xt_nt slot 0 (transposed)
__global__ __launch_bounds__(256) void attn_reduce(const u16* __restrict__ part, u16* __restrict__ attnT,
                                                   u16* __restrict__ xt_nt) {
  __shared__ u16 t[64][65];
  const int r0 = blockIdx.x * 64, c0 = blockIdx.y * 64;
  const int tid = threadIdx.x;
  const long gs = 512L * L;
#pragma unroll
  for (int s = 0; s < 16; ++s) {
    int idx = s * 256 + tid;
    int r = idx >> 6, c = idx & 63;
    long off = (long)(r0 + r) * L + c0 + c;
    float v = bf2f(part[off]) + bf2f(part[gs + off]) + bf2f(part[2 * gs + off]) + bf2f(part[3 * gs + off]);
    u16 u = f2bf(v);
    attnT[off] = u;
    t[r][c] = u;
  }
  __syncthreads();
  const int b = r0 >> 8, ch0 = r0 & 255;
#pragma unroll
  for (int s = 0; s < 16; ++s) {
    int idx = s * 256 + tid;
    int lr = idx >> 6, cc = idx & 63;
    xt_nt[((long)b * L + c0 + lr) * KC + 0 * C + ch0 + cc] = t[cc][lr];
  }
}

// ---------------- launcher ----------------

extern "C" void kernel_launch(void* const* d_in, const int* in_sizes, int n_in,
                              void* d_out, int out_size, void* d_ws, size_t ws_size,
                              hipStream_t stream) {
  const float* x     = (const float*)d_in[0];
  const float* lap   = (const float*)d_in[1];
  const float* gamma = (const float*)d_in[2];
  const float* beta  = (const float*)d_in[3];
  const float* w_qkv = (const float*)d_in[4];
  const float* w_out = (const float*)d_in[5];
  float* out = (float*)d_out;

  char* ws = (char*)d_ws;
  u16*   lap_bf = (u16*)ws;   ws += (size_t)L * L * 2;              // 32 MiB
  u16*   xt_nt  = (u16*)ws;   ws += (size_t)2 * L * KC * 2;        // 16 MiB
  u16*   xtT0   = (u16*)ws;   ws += (size_t)512 * L * 2;           // 4 MiB
  u16*   xtT1   = (u16*)ws;   ws += (size_t)512 * L * 2;
  u16*   xtT2   = (u16*)ws;   ws += (size_t)512 * L * 2;
  u16*   xtT3   = (u16*)ws;   ws += (size_t)512 * L * 2;
  char*  regA   = ws;         ws += (size_t)32 * 1024 * 1024;      // 32 MiB overlay region
  u16*   WqkvT  = (u16*)ws;   ws += (size_t)F3 * KC * 2;
  u16*   WoutT  = (u16*)ws;   ws += (size_t)C * KC * 2;
  float* gnst   = (float*)ws; ws += (size_t)64 * 8 * 2 * 4;

  // overlays (stream-ordered disjoint lifetimes):
  float* Ypart  = (float*)regA;                        // GEMM fp32 partials (32 MiB)
  u16*   qkv_bf = (u16*)regA;                          // qkv phase (12 MiB)
  u16*   VTb    = qkv_bf + (size_t)2 * L * F3;         // +4 MiB (ends exactly at 16 MiB)
  u16*   part   = (u16*)(regA + 16777216);             // attn bf16 partials [4][512][L] (16 MiB)
                                                       // DISJOINT from qkv_bf+VTb

  tobf16_kernel<<<dim3(8192), dim3(256), 0, stream>>>(lap, lap_bf, (long)L * L);
  transpose_w_kernel<<<dim3((F3 * KC + 255) / 256), dim3(256), 0, stream>>>(w_qkv, WqkvT, F3);
  transpose_w_kernel<<<dim3((C * KC + 255) / 256), dim3(256), 0, stream>>>(w_out, WoutT, C);
  gn_stats<<<dim3(64, 8), dim3(256), 0, stream>>>(x, gnst);
  gn_apply<<<dim3(64, 8), dim3(256), 0, stream>>>(x, gamma, beta, gnst, xtT0, xt_nt);

  // cheb conv 1 (split-K=4 lap GEMMs, 128x128 tiles, XCD-swizzled)
  gemm_bt<0,0,1><<<dim3(4, 32, 4), dim3(256), 0, stream>>>(xtT0, lap_bf, Ypart, 512, L, 1024, L);
  cheb_combine<<<dim3(8, 64), dim3(256), 0, stream>>>(Ypart, nullptr, xtT1, xt_nt, 1, 1.f);
  gemm_bt<0,0,1><<<dim3(4, 32, 4), dim3(256), 0, stream>>>(xtT1, lap_bf, Ypart, 512, L, 1024, L);
  cheb_combine<<<dim3(8, 64), dim3(256), 0, stream>>>(Ypart, xtT0, xtT2, xt_nt, 2, 2.f);
  gemm_bt<0,0,1><<<dim3(4, 32, 4), dim3(256), 0, stream>>>(xtT2, lap_bf, Ypart, 512, L, 1024, L);
  cheb_combine<<<dim3(8, 64), dim3(256), 0, stream>>>(Ypart, xtT1, xtT3, xt_nt, 3, 2.f);

  // qkv projection (Q columns pre-scaled by 1/16 for attention): N=768 = 6x128, 384 blocks (%8==0)
  gemm_bt<1,1,0><<<dim3(64, 6), dim3(256), 0, stream>>>(xt_nt, WqkvT, qkv_bf, 2 * L, F3, KC, KC);
  vt_kernel<<<dim3(8, 64), dim3(256), 0, stream>>>(qkv_bf, VTb);

  // fused attention (QBLK=64, XCD-swizzled): per-g bf16 partials then reduce
  attn_kernel<<<dim3(64, 4, 2), dim3(256), 0, stream>>>(qkv_bf, VTb, part);
  attn_reduce<<<dim3(8, 64), dim3(256), 0, stream>>>(part, xtT0, xt_nt);

  // cheb conv 2
  gemm_bt<0,0,1><<<dim3(4, 32, 4), dim3(256), 0, stream>>>(xtT0, lap_bf, Ypart, 512, L, 1024, L);
  cheb_combine<<<dim3(8, 64), dim3(256), 0, stream>>>(Ypart, nullptr, xtT1, xt_nt, 1, 1.f);
  gemm_bt<0,0,1><<<dim3(4, 32, 4), dim3(256), 0, stream>>>(Ypart ? xtT1 : xtT1, lap_bf, Ypart, 512, L, 1024, L);
  cheb_combine<<<dim3(8, 64), dim3(256), 0, stream>>>(Ypart, xtT0, xtT2, xt_nt, 2, 2.f);
  gemm_bt<0,0,1><<<dim3(4, 32, 4), dim3(256), 0, stream>>>(xtT2, lap_bf, Ypart, 512, L, 1024, L);
  cheb_combine<<<dim3(8, 64), dim3(256), 0, stream>>>(Ypart, xtT1, xtT3, xt_nt, 3, 2.f);

  // final projection split-K=4 + residual combine: N=256 = 2x128, 512 blocks
  gemm_bt<0,0,1><<<dim3(64, 2, 4), dim3(256), 0, stream>>>(xt_nt, WoutT, Ypart, 2 * L, C, 256, KC);
  out_combine<<<dim3(2048), dim3(256), 0, stream>>>(Ypart, x, out);
}